// Round 6
// baseline (1417.065 us; speedup 1.0000x reference)
//
#include <hip/hip_runtime.h>
#include <math.h>

#define N_NODES 100000
#define N_EDGES 1600000
#define HF 128
#define N_CLS 8
#define N_LAYERS 6
#define TILE_N 64
#define SCAN_B 1024
#define SCAN_NB ((N_NODES + SCAN_B - 1) / SCAN_B)   // 98
#define HBINS 8192
#define HCHUNK ((N_NODES + HBINS - 1) / HBINS)      // 13
#define HSLICE 8

// ---------------- in-degree histogram + per-edge rank (atomic return value) ----------------
__global__ void deg_rank_kernel(const int* __restrict__ dst,
                                int* __restrict__ ind, int* __restrict__ rank) {
    int e = blockIdx.x * blockDim.x + threadIdx.x;
    if (e < N_EDGES) {
        rank[e] = atomicAdd(&ind[dst[e]], 1);
    }
}

// ---------------- out-degree histogram via chunked LDS bins ----------------
__global__ __launch_bounds__(1024) void outdeg_hist_kernel(const int* __restrict__ src,
                                                           int* __restrict__ outd) {
    __shared__ int hist[HBINS];
    int chunk = blockIdx.x;          // 0..HCHUNK-1
    int slice = blockIdx.y;          // 0..HSLICE-1
    int lo = chunk * HBINS;
    int hi = lo + HBINS;
    for (int i = threadIdx.x; i < HBINS; i += 1024) hist[i] = 0;
    __syncthreads();
    const int4* s4 = (const int4*)src;
    const int n4 = N_EDGES / 4;      // 400000
    int per = (n4 + HSLICE - 1) / HSLICE;
    int beg = slice * per;
    int end = beg + per; if (end > n4) end = n4;
    for (int i = beg + threadIdx.x; i < end; i += 1024) {
        int4 v = s4[i];
        if (v.x >= lo && v.x < hi) atomicAdd(&hist[v.x - lo], 1);
        if (v.y >= lo && v.y < hi) atomicAdd(&hist[v.y - lo], 1);
        if (v.z >= lo && v.z < hi) atomicAdd(&hist[v.z - lo], 1);
        if (v.w >= lo && v.w < hi) atomicAdd(&hist[v.w - lo], 1);
    }
    __syncthreads();
    for (int i = threadIdx.x; i < HBINS; i += 1024) {
        int c = hist[i];
        if (c != 0 && lo + i < N_NODES) atomicAdd(&outd[lo + i], c);
    }
}

// ---------------- norms ----------------
__global__ void norm_kernel(const int* __restrict__ outd, const int* __restrict__ ind,
                            float* __restrict__ ns, float* __restrict__ nd) {
    int n = blockIdx.x * blockDim.x + threadIdx.x;
    if (n < N_NODES) {
        int od = outd[n]; if (od < 1) od = 1;
        int id = ind[n];  if (id < 1) id = 1;
        ns[n] = rsqrtf((float)od);
        nd[n] = rsqrtf((float)id);
    }
}

// ---------------- hierarchical scan: stage 1 (per-block inclusive scan) ----------------
__global__ __launch_bounds__(SCAN_B) void scan1_kernel(const int* __restrict__ deg,
                                                       int* __restrict__ incl,
                                                       int* __restrict__ bsum) {
    __shared__ int buf[SCAN_B];
    int t = threadIdx.x;
    int g = blockIdx.x * SCAN_B + t;
    int v = (g < N_NODES) ? deg[g] : 0;
    buf[t] = v;
    __syncthreads();
    #pragma unroll
    for (int off = 1; off < SCAN_B; off <<= 1) {
        int add = (t >= off) ? buf[t - off] : 0;
        __syncthreads();
        buf[t] += add;
        __syncthreads();
    }
    if (g < N_NODES) incl[g] = buf[t];
    if (t == SCAN_B - 1) bsum[blockIdx.x] = buf[t];
}

// ---------------- stage 2: scan the block sums (1 block, 128 threads) ----------------
__global__ __launch_bounds__(128) void scan2_kernel(int* __restrict__ bsum) {
    __shared__ int buf[128];
    int t = threadIdx.x;
    buf[t] = (t < SCAN_NB) ? bsum[t] : 0;
    __syncthreads();
    #pragma unroll
    for (int off = 1; off < 128; off <<= 1) {
        int add = (t >= off) ? buf[t - off] : 0;
        __syncthreads();
        buf[t] += add;
        __syncthreads();
    }
    if (t < SCAN_NB) bsum[t] = buf[t];   // inclusive scan of block sums
}

// ---------------- stage 3: apply offsets -> exclusive row_ptr ----------------
__global__ __launch_bounds__(SCAN_B) void scan3_kernel(const int* __restrict__ deg,
                                                       const int* __restrict__ incl,
                                                       const int* __restrict__ bsum,
                                                       int* __restrict__ row_ptr) {
    int t = threadIdx.x;
    int g = blockIdx.x * SCAN_B + t;
    if (g < N_NODES) {
        int off = (blockIdx.x > 0) ? bsum[blockIdx.x - 1] : 0;
        row_ptr[g] = off + incl[g] - deg[g];
    }
    if (g == 0) row_ptr[N_NODES] = bsum[SCAN_NB - 1];
}

// ------- scatter edges into CSR (atomic-free); pack (src,w*ns*nd) as float2 -------
__global__ void scatter2_kernel(const int* __restrict__ src, const int* __restrict__ dst,
                                const float* __restrict__ ew, const float* __restrict__ ns,
                                const float* __restrict__ nd, const int* __restrict__ row_ptr,
                                const int* __restrict__ rank, float2* __restrict__ esw) {
    int e = blockIdx.x * blockDim.x + threadIdx.x;
    if (e < N_EDGES) {
        int s = src[e];
        int d = dst[e];
        int pos = row_ptr[d] + rank[e];
        esw[pos] = make_float2(__int_as_float(s), ew[e] * ns[s] * nd[d]);
    }
}

// ---- fp32 GEMM: Y[n][f] = sum_k X[n][k] W[k][f]; 64-node tile, acc 4n x 8f ----
__global__ __launch_bounds__(256) void gemm_kernel(const float* __restrict__ X,
                                                   const float* __restrict__ W,
                                                   float* __restrict__ Y) {
    __shared__ float Xs[TILE_N][HF + 4];   // stride 132 floats (528B): wave's 4 ty rows
                                           // land on banks 0/4/8/12 -> conflict-free b128
    int tid = threadIdx.x;
    int nodeBase = blockIdx.x * TILE_N;

    for (int idx = tid; idx < TILE_N * (HF / 4); idx += 256) {
        int r = idx >> 5;
        int c = idx & 31;
        int n = nodeBase + r;
        float4 v = make_float4(0.f, 0.f, 0.f, 0.f);
        if (n < N_NODES) v = ((const float4*)(X + (size_t)n * HF))[c];
        *(float4*)(&Xs[r][c * 4]) = v;
    }
    __syncthreads();

    int tx = tid & 15;   // feature columns: f4 at tx and tx+16
    int ty = tid >> 4;   // node = ty + 16*i, i=0..3

    float acc[4][8];
    #pragma unroll
    for (int i = 0; i < 4; i++)
        #pragma unroll
        for (int j = 0; j < 8; j++) acc[i][j] = 0.f;

    const float4* W4 = (const float4*)W;

    #pragma unroll 2
    for (int k4 = 0; k4 < HF / 4; k4++) {
        float4 w0[4], w1[4];
        #pragma unroll
        for (int kk = 0; kk < 4; kk++) {
            w0[kk] = W4[(k4 * 4 + kk) * 32 + tx];
            w1[kk] = W4[(k4 * 4 + kk) * 32 + 16 + tx];
        }
        float4 xv[4];
        #pragma unroll
        for (int i = 0; i < 4; i++)
            xv[i] = *(const float4*)(&Xs[ty + 16 * i][k4 * 4]);
        #pragma unroll
        for (int i = 0; i < 4; i++) {
            acc[i][0] += xv[i].x * w0[0].x; acc[i][1] += xv[i].x * w0[0].y;
            acc[i][2] += xv[i].x * w0[0].z; acc[i][3] += xv[i].x * w0[0].w;
            acc[i][4] += xv[i].x * w1[0].x; acc[i][5] += xv[i].x * w1[0].y;
            acc[i][6] += xv[i].x * w1[0].z; acc[i][7] += xv[i].x * w1[0].w;

            acc[i][0] += xv[i].y * w0[1].x; acc[i][1] += xv[i].y * w0[1].y;
            acc[i][2] += xv[i].y * w0[1].z; acc[i][3] += xv[i].y * w0[1].w;
            acc[i][4] += xv[i].y * w1[1].x; acc[i][5] += xv[i].y * w1[1].y;
            acc[i][6] += xv[i].y * w1[1].z; acc[i][7] += xv[i].y * w1[1].w;

            acc[i][0] += xv[i].z * w0[2].x; acc[i][1] += xv[i].z * w0[2].y;
            acc[i][2] += xv[i].z * w0[2].z; acc[i][3] += xv[i].z * w0[2].w;
            acc[i][4] += xv[i].z * w1[2].x; acc[i][5] += xv[i].z * w1[2].y;
            acc[i][6] += xv[i].z * w1[2].z; acc[i][7] += xv[i].z * w1[2].w;

            acc[i][0] += xv[i].w * w0[3].x; acc[i][1] += xv[i].w * w0[3].y;
            acc[i][2] += xv[i].w * w0[3].z; acc[i][3] += xv[i].w * w0[3].w;
            acc[i][4] += xv[i].w * w1[3].x; acc[i][5] += xv[i].w * w1[3].y;
            acc[i][6] += xv[i].w * w1[3].z; acc[i][7] += xv[i].w * w1[3].w;
        }
    }

    #pragma unroll
    for (int i = 0; i < 4; i++) {
        int n = nodeBase + ty + 16 * i;
        if (n < N_NODES) {
            float4* yrow = (float4*)(Y + (size_t)n * HF);
            yrow[tx]      = make_float4(acc[i][0], acc[i][1], acc[i][2], acc[i][3]);
            yrow[16 + tx] = make_float4(acc[i][4], acc[i][5], acc[i][6], acc[i][7]);
        }
    }
}

// ------- aggregation: wave per node, 2x-unrolled CSR walk, packed esw -------
__global__ __launch_bounds__(256) void agg_kernel(const float* __restrict__ hl,
                                                  const int* __restrict__ row_ptr,
                                                  const float2* __restrict__ esw,
                                                  const float* __restrict__ bias,
                                                  float* __restrict__ out) {
    int node = blockIdx.x * 4 + (threadIdx.x >> 6);
    if (node >= N_NODES) return;
    int lane = threadIdx.x & 63;

    int beg = row_ptr[node];
    int end = row_ptr[node + 1];
    float ax = 0.f, ay = 0.f;
    int i = beg;
    for (; i + 2 <= end; i += 2) {
        float2 p0 = esw[i];
        float2 p1 = esw[i + 1];
        int s0 = __float_as_int(p0.x);
        int s1 = __float_as_int(p1.x);
        float2 v0 = ((const float2*)(hl + (size_t)s0 * HF))[lane];
        float2 v1 = ((const float2*)(hl + (size_t)s1 * HF))[lane];
        ax += v0.x * p0.y; ay += v0.y * p0.y;
        ax += v1.x * p1.y; ay += v1.y * p1.y;
    }
    if (i < end) {
        float2 p = esw[i];
        int s = __float_as_int(p.x);
        float2 v = ((const float2*)(hl + (size_t)s * HF))[lane];
        ax += v.x * p.y; ay += v.y * p.y;
    }
    float2 bb = ((const float2*)bias)[lane];
    float ox = ax + bb.x;
    float oy = ay + bb.y;
    ox = (ox > 0.f) ? ox : 0.01f * ox;
    oy = (oy > 0.f) ? oy : 0.01f * oy;
    ((float2*)(out + (size_t)node * HF))[lane] = make_float2(ox, oy);
}

// ---------------- final projection: wave per node, 8 classes ----------------
__global__ __launch_bounds__(256) void proj_kernel(const float* __restrict__ h,
                                                   const float* __restrict__ W,
                                                   const float* __restrict__ b,
                                                   float* __restrict__ out) {
    int node = blockIdx.x * (blockDim.x >> 6) + (threadIdx.x >> 6);
    if (node >= N_NODES) return;
    int lane = threadIdx.x & 63;

    float2 v = *(const float2*)(h + (size_t)node * HF + lane * 2);
    float acc[N_CLS];
    #pragma unroll
    for (int c = 0; c < N_CLS; c++) {
        acc[c] = v.x * W[(lane * 2) * N_CLS + c] + v.y * W[(lane * 2 + 1) * N_CLS + c];
    }
    #pragma unroll
    for (int off = 32; off > 0; off >>= 1) {
        #pragma unroll
        for (int c = 0; c < N_CLS; c++) acc[c] += __shfl_down(acc[c], off);
    }
    if (lane == 0) {
        #pragma unroll
        for (int c = 0; c < N_CLS; c++) out[(size_t)node * N_CLS + c] = acc[c] + b[c];
    }
}

// ---------------- launch ----------------
extern "C" void kernel_launch(void* const* d_in, const int* in_sizes, int n_in,
                              void* d_out, int out_size, void* d_ws, size_t ws_size,
                              hipStream_t stream) {
    const float* in_feat = (const float*)d_in[0];
    const int*   src     = (const int*)d_in[1];
    const int*   dst     = (const int*)d_in[2];
    const float* ew      = (const float*)d_in[3];
    const float* conv_W  = (const float*)d_in[4];
    const float* conv_b  = (const float*)d_in[5];
    const float* lin_W   = (const float*)d_in[6];
    const float* lin_b   = (const float*)d_in[7];
    float* out = (float*)d_out;

    char* p = (char*)d_ws;
    float* hA = (float*)p;        p += (size_t)N_NODES * HF * sizeof(float);
    float* hB = (float*)p;        p += (size_t)N_NODES * HF * sizeof(float);
    float2* esw = (float2*)p;     p += (size_t)N_EDGES * sizeof(float2);
    int*   row_ptr = (int*)p;     p += ((size_t)N_NODES + 8) * sizeof(int);
    int*   out_deg = (int*)p;     p += (size_t)N_NODES * sizeof(int);
    int*   in_deg = (int*)p;      p += (size_t)N_NODES * sizeof(int);
    float* norm_src = (float*)p;  p += (size_t)N_NODES * sizeof(float);
    float* norm_dst = (float*)p;  p += (size_t)N_NODES * sizeof(float);
    int*   incl = (int*)p;        p += (size_t)N_NODES * sizeof(int);
    int*   bsum = (int*)p;        p += 256 * sizeof(int);
    // rank aliases hB: rank is dead before the first gemm writes hB
    int*   rank = (int*)hB;
    (void)p; (void)ws_size; (void)in_sizes; (void)n_in; (void)out_size;

    hipMemsetAsync(out_deg, 0, (size_t)N_NODES * sizeof(int), stream);
    hipMemsetAsync(in_deg, 0, (size_t)N_NODES * sizeof(int), stream);

    int egrid = (N_EDGES + 255) / 256;
    int ngrid = (N_NODES + 255) / 256;

    deg_rank_kernel<<<egrid, 256, 0, stream>>>(dst, in_deg, rank);
    outdeg_hist_kernel<<<dim3(HCHUNK, HSLICE), 1024, 0, stream>>>(src, out_deg);
    norm_kernel<<<ngrid, 256, 0, stream>>>(out_deg, in_deg, norm_src, norm_dst);
    scan1_kernel<<<SCAN_NB, SCAN_B, 0, stream>>>(in_deg, incl, bsum);
    scan2_kernel<<<1, 128, 0, stream>>>(bsum);
    scan3_kernel<<<SCAN_NB, SCAN_B, 0, stream>>>(in_deg, incl, bsum, row_ptr);
    scatter2_kernel<<<egrid, 256, 0, stream>>>(src, dst, ew, norm_src, norm_dst,
                                               row_ptr, rank, esw);

    int ggrid = (N_NODES + TILE_N - 1) / TILE_N;
    int agrid = (N_NODES + 3) / 4;   // 4 nodes (waves) per 256-thread block

    const float* cur = in_feat;
    for (int l = 0; l < N_LAYERS; l++) {
        gemm_kernel<<<ggrid, 256, 0, stream>>>(cur, conv_W + (size_t)l * HF * HF, hB);
        agg_kernel<<<agrid, 256, 0, stream>>>(hB, row_ptr, esw,
                                              conv_b + (size_t)l * HF, hA);
        cur = hA;
    }
    proj_kernel<<<agrid, 256, 0, stream>>>(hA, lin_W, lin_b, out);
}

// Round 7
// 1303.775 us; speedup vs baseline: 1.0869x; 1.0869x over previous
//
#include <hip/hip_runtime.h>
#include <math.h>

#define N_NODES 100000
#define N_EDGES 1600000
#define HF 128
#define N_CLS 8
#define N_LAYERS 6
#define TILE_N 64
#define SCAN_B 1024
#define SCAN_NB ((N_NODES + SCAN_B - 1) / SCAN_B)   // 98
#define HBINS 8192
#define HCHUNK ((N_NODES + HBINS - 1) / HBINS)      // 13
#define HSLICE 8

// ---------------- in-degree histogram + per-edge rank (atomic return value) ----------------
__global__ void deg_rank_kernel(const int* __restrict__ dst,
                                int* __restrict__ ind, int* __restrict__ rank) {
    int e = blockIdx.x * blockDim.x + threadIdx.x;
    if (e < N_EDGES) {
        rank[e] = atomicAdd(&ind[dst[e]], 1);
    }
}

// ---------------- out-degree histogram via chunked LDS bins ----------------
__global__ __launch_bounds__(1024) void outdeg_hist_kernel(const int* __restrict__ src,
                                                           int* __restrict__ outd) {
    __shared__ int hist[HBINS];
    int chunk = blockIdx.x;          // 0..HCHUNK-1
    int slice = blockIdx.y;          // 0..HSLICE-1
    int lo = chunk * HBINS;
    int hi = lo + HBINS;
    for (int i = threadIdx.x; i < HBINS; i += 1024) hist[i] = 0;
    __syncthreads();
    const int4* s4 = (const int4*)src;
    const int n4 = N_EDGES / 4;      // 400000
    int per = (n4 + HSLICE - 1) / HSLICE;
    int beg = slice * per;
    int end = beg + per; if (end > n4) end = n4;
    for (int i = beg + threadIdx.x; i < end; i += 1024) {
        int4 v = s4[i];
        if (v.x >= lo && v.x < hi) atomicAdd(&hist[v.x - lo], 1);
        if (v.y >= lo && v.y < hi) atomicAdd(&hist[v.y - lo], 1);
        if (v.z >= lo && v.z < hi) atomicAdd(&hist[v.z - lo], 1);
        if (v.w >= lo && v.w < hi) atomicAdd(&hist[v.w - lo], 1);
    }
    __syncthreads();
    for (int i = threadIdx.x; i < HBINS; i += 1024) {
        int c = hist[i];
        if (c != 0 && lo + i < N_NODES) atomicAdd(&outd[lo + i], c);
    }
}

// ---------------- norms ----------------
__global__ void norm_kernel(const int* __restrict__ outd, const int* __restrict__ ind,
                            float* __restrict__ ns, float* __restrict__ nd) {
    int n = blockIdx.x * blockDim.x + threadIdx.x;
    if (n < N_NODES) {
        int od = outd[n]; if (od < 1) od = 1;
        int id = ind[n];  if (id < 1) id = 1;
        ns[n] = rsqrtf((float)od);
        nd[n] = rsqrtf((float)id);
    }
}

// ---------------- hierarchical scan: stage 1 (per-block inclusive scan) ----------------
__global__ __launch_bounds__(SCAN_B) void scan1_kernel(const int* __restrict__ deg,
                                                       int* __restrict__ incl,
                                                       int* __restrict__ bsum) {
    __shared__ int buf[SCAN_B];
    int t = threadIdx.x;
    int g = blockIdx.x * SCAN_B + t;
    int v = (g < N_NODES) ? deg[g] : 0;
    buf[t] = v;
    __syncthreads();
    #pragma unroll
    for (int off = 1; off < SCAN_B; off <<= 1) {
        int add = (t >= off) ? buf[t - off] : 0;
        __syncthreads();
        buf[t] += add;
        __syncthreads();
    }
    if (g < N_NODES) incl[g] = buf[t];
    if (t == SCAN_B - 1) bsum[blockIdx.x] = buf[t];
}

// ---------------- stage 2: scan the block sums (1 block, 128 threads) ----------------
__global__ __launch_bounds__(128) void scan2_kernel(int* __restrict__ bsum) {
    __shared__ int buf[128];
    int t = threadIdx.x;
    buf[t] = (t < SCAN_NB) ? bsum[t] : 0;
    __syncthreads();
    #pragma unroll
    for (int off = 1; off < 128; off <<= 1) {
        int add = (t >= off) ? buf[t - off] : 0;
        __syncthreads();
        buf[t] += add;
        __syncthreads();
    }
    if (t < SCAN_NB) bsum[t] = buf[t];   // inclusive scan of block sums
}

// ---------------- stage 3: apply offsets -> exclusive row_ptr ----------------
__global__ __launch_bounds__(SCAN_B) void scan3_kernel(const int* __restrict__ deg,
                                                       const int* __restrict__ incl,
                                                       const int* __restrict__ bsum,
                                                       int* __restrict__ row_ptr) {
    int t = threadIdx.x;
    int g = blockIdx.x * SCAN_B + t;
    if (g < N_NODES) {
        int off = (blockIdx.x > 0) ? bsum[blockIdx.x - 1] : 0;
        row_ptr[g] = off + incl[g] - deg[g];
    }
    if (g == 0) row_ptr[N_NODES] = bsum[SCAN_NB - 1];
}

// ------- scatter edges into CSR (atomic-free); pack (src,w*ns*nd) as float2 -------
__global__ void scatter2_kernel(const int* __restrict__ src, const int* __restrict__ dst,
                                const float* __restrict__ ew, const float* __restrict__ ns,
                                const float* __restrict__ nd, const int* __restrict__ row_ptr,
                                const int* __restrict__ rank, float2* __restrict__ esw) {
    int e = blockIdx.x * blockDim.x + threadIdx.x;
    if (e < N_EDGES) {
        int s = src[e];
        int d = dst[e];
        int pos = row_ptr[d] + rank[e];
        esw[pos] = make_float2(__int_as_float(s), ew[e] * ns[s] * nd[d]);
    }
}

// ---------------- fp32 GEMM (R4 shape): Y[n][f] = sum_k X[n][k] W[k][f] ----------------
__global__ __launch_bounds__(256) void gemm_kernel(const float* __restrict__ X,
                                                   const float* __restrict__ W,
                                                   float* __restrict__ Y) {
    __shared__ float Xs[TILE_N][HF];   // 32 KB
    int tid = threadIdx.x;
    int nodeBase = blockIdx.x * TILE_N;

    for (int i = tid; i < TILE_N * (HF / 4); i += 256) {
        int r = i >> 5;
        int c = i & 31;
        int n = nodeBase + r;
        float4 v = make_float4(0.f, 0.f, 0.f, 0.f);
        if (n < N_NODES) v = ((const float4*)(X + (size_t)n * HF))[c];
        ((float4*)(&Xs[r][0]))[c] = v;
    }
    __syncthreads();

    int tx = tid & 31;
    int ty = tid >> 5;

    float acc[8][4];
    #pragma unroll
    for (int i = 0; i < 8; i++)
        #pragma unroll
        for (int j = 0; j < 4; j++) acc[i][j] = 0.f;

    const float4* W4 = (const float4*)W;

    for (int k4 = 0; k4 < HF / 4; k4++) {
        float4 wv0 = W4[(k4 * 4 + 0) * 32 + tx];
        float4 wv1 = W4[(k4 * 4 + 1) * 32 + tx];
        float4 wv2 = W4[(k4 * 4 + 2) * 32 + tx];
        float4 wv3 = W4[(k4 * 4 + 3) * 32 + tx];
        #pragma unroll
        for (int i = 0; i < 8; i++) {
            float4 xv = ((const float4*)(&Xs[ty + 8 * i][0]))[k4];
            acc[i][0] += xv.x * wv0.x; acc[i][1] += xv.x * wv0.y;
            acc[i][2] += xv.x * wv0.z; acc[i][3] += xv.x * wv0.w;
            acc[i][0] += xv.y * wv1.x; acc[i][1] += xv.y * wv1.y;
            acc[i][2] += xv.y * wv1.z; acc[i][3] += xv.y * wv1.w;
            acc[i][0] += xv.z * wv2.x; acc[i][1] += xv.z * wv2.y;
            acc[i][2] += xv.z * wv2.z; acc[i][3] += xv.z * wv2.w;
            acc[i][0] += xv.w * wv3.x; acc[i][1] += xv.w * wv3.y;
            acc[i][2] += xv.w * wv3.z; acc[i][3] += xv.w * wv3.w;
        }
    }

    #pragma unroll
    for (int i = 0; i < 8; i++) {
        int n = nodeBase + ty + 8 * i;
        if (n < N_NODES) {
            float4 o = make_float4(acc[i][0], acc[i][1], acc[i][2], acc[i][3]);
            ((float4*)(Y + (size_t)n * HF))[tx] = o;
        }
    }
}

// ------- aggregation: wave per node, paired float4 gathers (2 edges / instruction) -------
// lanes 0-31 process even edges (features 4*fl..4*fl+3), lanes 32-63 odd edges;
// cross-half combine via shfl_xor(32) at the end.
__global__ __launch_bounds__(256) void agg_kernel(const float* __restrict__ hl,
                                                  const int* __restrict__ row_ptr,
                                                  const float2* __restrict__ esw,
                                                  const float* __restrict__ bias,
                                                  float* __restrict__ out) {
    int node = blockIdx.x * 4 + (threadIdx.x >> 6);
    if (node >= N_NODES) return;
    int lane = threadIdx.x & 63;
    int half = lane >> 5;        // 0: even edge of pair, 1: odd edge
    int fl = lane & 31;          // float4 index within row

    int beg = row_ptr[node];
    int end = row_ptr[node + 1];
    float ax = 0.f, ay = 0.f, az = 0.f, aw = 0.f;

    int i = beg;
    for (; i + 2 <= end; i += 2) {
        float2 p = esw[i + half];                    // broadcast per half-wave
        int s = __float_as_int(p.x);
        float4 v = ((const float4*)(hl + (size_t)s * HF))[fl];
        ax += v.x * p.y; ay += v.y * p.y;
        az += v.z * p.y; aw += v.w * p.y;
    }
    if (i < end && half == 0) {                      // tail edge: half 0 only
        float2 p = esw[i];
        int s = __float_as_int(p.x);
        float4 v = ((const float4*)(hl + (size_t)s * HF))[fl];
        ax += v.x * p.y; ay += v.y * p.y;
        az += v.z * p.y; aw += v.w * p.y;
    }

    // combine even/odd halves (same feature quad lives at lane ^ 32)
    ax += __shfl_xor(ax, 32);
    ay += __shfl_xor(ay, 32);
    az += __shfl_xor(az, 32);
    aw += __shfl_xor(aw, 32);

    if (half == 0) {
        float4 bb = ((const float4*)bias)[fl];
        float ox = ax + bb.x;
        float oy = ay + bb.y;
        float oz = az + bb.z;
        float ow = aw + bb.w;
        ox = (ox > 0.f) ? ox : 0.01f * ox;
        oy = (oy > 0.f) ? oy : 0.01f * oy;
        oz = (oz > 0.f) ? oz : 0.01f * oz;
        ow = (ow > 0.f) ? ow : 0.01f * ow;
        ((float4*)(out + (size_t)node * HF))[fl] = make_float4(ox, oy, oz, ow);
    }
}

// ---------------- final projection: wave per node, 8 classes ----------------
__global__ __launch_bounds__(256) void proj_kernel(const float* __restrict__ h,
                                                   const float* __restrict__ W,
                                                   const float* __restrict__ b,
                                                   float* __restrict__ out) {
    int node = blockIdx.x * (blockDim.x >> 6) + (threadIdx.x >> 6);
    if (node >= N_NODES) return;
    int lane = threadIdx.x & 63;

    float2 v = *(const float2*)(h + (size_t)node * HF + lane * 2);
    float acc[N_CLS];
    #pragma unroll
    for (int c = 0; c < N_CLS; c++) {
        acc[c] = v.x * W[(lane * 2) * N_CLS + c] + v.y * W[(lane * 2 + 1) * N_CLS + c];
    }
    #pragma unroll
    for (int off = 32; off > 0; off >>= 1) {
        #pragma unroll
        for (int c = 0; c < N_CLS; c++) acc[c] += __shfl_down(acc[c], off);
    }
    if (lane == 0) {
        #pragma unroll
        for (int c = 0; c < N_CLS; c++) out[(size_t)node * N_CLS + c] = acc[c] + b[c];
    }
}

// ---------------- launch ----------------
extern "C" void kernel_launch(void* const* d_in, const int* in_sizes, int n_in,
                              void* d_out, int out_size, void* d_ws, size_t ws_size,
                              hipStream_t stream) {
    const float* in_feat = (const float*)d_in[0];
    const int*   src     = (const int*)d_in[1];
    const int*   dst     = (const int*)d_in[2];
    const float* ew      = (const float*)d_in[3];
    const float* conv_W  = (const float*)d_in[4];
    const float* conv_b  = (const float*)d_in[5];
    const float* lin_W   = (const float*)d_in[6];
    const float* lin_b   = (const float*)d_in[7];
    float* out = (float*)d_out;

    char* p = (char*)d_ws;
    float* hA = (float*)p;        p += (size_t)N_NODES * HF * sizeof(float);
    float* hB = (float*)p;        p += (size_t)N_NODES * HF * sizeof(float);
    float2* esw = (float2*)p;     p += (size_t)N_EDGES * sizeof(float2);
    int*   row_ptr = (int*)p;     p += ((size_t)N_NODES + 8) * sizeof(int);
    int*   out_deg = (int*)p;     p += (size_t)N_NODES * sizeof(int);
    int*   in_deg = (int*)p;      p += (size_t)N_NODES * sizeof(int);
    float* norm_src = (float*)p;  p += (size_t)N_NODES * sizeof(float);
    float* norm_dst = (float*)p;  p += (size_t)N_NODES * sizeof(float);
    int*   incl = (int*)p;        p += (size_t)N_NODES * sizeof(int);
    int*   bsum = (int*)p;        p += 256 * sizeof(int);
    // rank aliases hB: rank is dead before the first gemm writes hB
    int*   rank = (int*)hB;
    (void)p; (void)ws_size; (void)in_sizes; (void)n_in; (void)out_size;

    hipMemsetAsync(out_deg, 0, (size_t)N_NODES * sizeof(int), stream);
    hipMemsetAsync(in_deg, 0, (size_t)N_NODES * sizeof(int), stream);

    int egrid = (N_EDGES + 255) / 256;
    int ngrid = (N_NODES + 255) / 256;

    deg_rank_kernel<<<egrid, 256, 0, stream>>>(dst, in_deg, rank);
    outdeg_hist_kernel<<<dim3(HCHUNK, HSLICE), 1024, 0, stream>>>(src, out_deg);
    norm_kernel<<<ngrid, 256, 0, stream>>>(out_deg, in_deg, norm_src, norm_dst);
    scan1_kernel<<<SCAN_NB, SCAN_B, 0, stream>>>(in_deg, incl, bsum);
    scan2_kernel<<<1, 128, 0, stream>>>(bsum);
    scan3_kernel<<<SCAN_NB, SCAN_B, 0, stream>>>(in_deg, incl, bsum, row_ptr);
    scatter2_kernel<<<egrid, 256, 0, stream>>>(src, dst, ew, norm_src, norm_dst,
                                               row_ptr, rank, esw);

    int ggrid = (N_NODES + TILE_N - 1) / TILE_N;
    int agrid = (N_NODES + 3) / 4;   // 4 nodes (waves) per 256-thread block

    const float* cur = in_feat;
    for (int l = 0; l < N_LAYERS; l++) {
        gemm_kernel<<<ggrid, 256, 0, stream>>>(cur, conv_W + (size_t)l * HF * HF, hB);
        agg_kernel<<<agrid, 256, 0, stream>>>(hB, row_ptr, esw,
                                              conv_b + (size_t)l * HF, hA);
        cur = hA;
    }
    proj_kernel<<<agrid, 256, 0, stream>>>(hA, lin_W, lin_b, out);
}